// Round 3
// baseline (4379.755 us; speedup 1.0000x reference)
//
#include <hip/hip_runtime.h>
#include <stdint.h>

// LSTM: B=64 S=512 IN=HID=1024, fp32 in/out.
// d_in: x(64,512,1024) U(1024,4096) V(1024,4096) B(4096) h0(64,1024) c0(64,1024)
// d_out: out(64,512,1024) ++ h_fin(64,1024) ++ c_fin(64,1024)
//
// G = x@U precomputed as one big bf16 MFMA GEMM. Persistent kernel runs the
// 512-step recurrence with V stationary in VGPRs as MFMA B-frags.
//
// Sync protocol history:
//  R3: flag-release raced (flag visible at MALL before write-through data).
//  R4: TAG-IN-DATA — h exchanged as u32 = bf16(h)<<16 | step_tag; readers
//      bulk-load (sc0 sc1) and re-pass until all tags match.
//  R5: divergent per-fragment retry — REGRESSED (serialized MALL RTs).
//  R6: flag-as-hint before bulk pass: 2429→2280us only. Post-mortem: cost is
//      the per-step serial MALL latency chain (store drain → flag publish →
//      flag observe → bulk RT), not redundant traffic. Blocks idle during it.
//  R7: DEPTH-2 PIPELINE. Grid 128; each block owns TWO independent batch
//      groups (A,B) and alternates slots: while A's stores/flags propagate,
//      the block runs B's whole slot. Flag publish for A is deferred into B's
//      flag-spin (after its vmcnt(0), which drains A's h store in per-wave
//      program order). Per-wave flags (dwordx4 check) remove __syncthreads
//      from the publish path; raw s_barrier + lgkmcnt keeps the compiler's
//      vmcnt(0)-before-barrier drain off the critical path. Tags remain the
//      correctness backstop (flags are hints only).

#define OUT_HF  33554432
#define OUT_CF  33619968

typedef __attribute__((ext_vector_type(8))) short bf16x8;
typedef __attribute__((ext_vector_type(4))) float f32x4;
typedef __attribute__((ext_vector_type(4))) unsigned short u16x4;
typedef __attribute__((ext_vector_type(4))) unsigned int u32x4;

// ---- ws layout (bytes) ----
#define WS_G    0                 // bf16 G[32768][4096]    268435456
#define WS_XB   268435456         // bf16 x  [32768][1024]   67108864 (dead after gemm)
#define WS_HB   268435456         // u32 hbuf[2][64][1024]     524288 (aliases XB; init_h runs after gemm)
#define WS_FL   268959744         // u32 flags[4][64][4]          4096 (aliases XB too)
#define WS_UT   335544320         // bf16 U^T[4096][1024]     8388608

__device__ __forceinline__ unsigned short f2bf(float f) {
  unsigned u = __float_as_uint(f);
  u += 0x7FFFu + ((u >> 16) & 1u);          // RNE
  return (unsigned short)(u >> 16);
}
__device__ __forceinline__ float bf2f(unsigned short b) {
  return __uint_as_float(((unsigned)b) << 16);
}
__device__ __forceinline__ float sigf(float x)   { return 1.0f / (1.0f + __expf(-x)); }
__device__ __forceinline__ float tanhf_(float x) { return 2.0f / (1.0f + __expf(-2.0f * x)) - 1.0f; }

// ---------------- x fp32 -> bf16 ----------------
__global__ void convert_x(const float* __restrict__ x, unsigned short* __restrict__ xb) {
  const int i = (blockIdx.x * 256 + threadIdx.x) * 4;   // grid 32768
  f32x4 v = *(const f32x4*)(x + i);
  u16x4 o;
  o[0] = f2bf(v[0]); o[1] = f2bf(v[1]); o[2] = f2bf(v[2]); o[3] = f2bf(v[3]);
  *(u16x4*)(xb + i) = o;
}

// ---------------- U fp32 (1024x4096) -> bf16 U^T (4096x1024) ----------------
__global__ void transpose_u(const float* __restrict__ U, unsigned short* __restrict__ ut) {
  __shared__ unsigned short t[64 * 65];
  const int kt = blockIdx.x;      // 16
  const int nt = blockIdx.y;      // 64
  const int tid = threadIdx.x;
  const int nn = tid & 63, kq = tid >> 6;
  #pragma unroll
  for (int i = 0; i < 16; ++i) {
    const int kk = kq * 16 + i;
    t[kk * 65 + nn] = f2bf(U[(size_t)(kt * 64 + kk) * 4096 + nt * 64 + nn]);
  }
  __syncthreads();
  const int kk2 = tid & 63, nq = tid >> 6;
  #pragma unroll
  for (int i = 0; i < 16; ++i) {
    const int nn2 = nq * 16 + i;
    ut[(size_t)(nt * 64 + nn2) * 1024 + kt * 64 + kk2] = t[kk2 * 65 + nn2];
  }
}

// ---------------- init: h0 -> tagged u32 buffer + zero flags ----------------
__global__ void init_h(const float* __restrict__ h0, uint32_t* __restrict__ hb32,
                       uint32_t* __restrict__ flags) {
  const int i = blockIdx.x * 256 + threadIdx.x;   // grid 256 -> 65536
  const uint32_t w0 = ((uint32_t)f2bf(h0[i])) << 16;   // tag 0
  const uint32_t w1 = 0xFFFFFFFFu;                     // tag 0xFFFF: never matches
  const uint32_t* p0 = hb32 + i;
  const uint32_t* p1 = hb32 + 65536 + i;
  asm volatile("global_store_dword %0, %2, off sc0 sc1\n\t"
               "global_store_dword %1, %3, off sc0 sc1"
               :: "v"(p0), "v"(p1), "v"(w0), "v"(w1) : "memory");
  if (i < 1024) {   // flags[4][64][4] = 0 : "step-0 h is ready" (matches tag-0 data)
    const uint32_t* fp = flags + i;
    const uint32_t z = 0u;
    asm volatile("global_store_dword %0, %1, off sc0 sc1"
                 :: "v"(fp), "v"(z) : "memory");
  }
}

// ---------------- G = x @ U  (bf16 MFMA, 128x128x32 tiles) ----------------
__global__ void __launch_bounds__(256) gemm_xu(const unsigned short* __restrict__ A,
                                               const unsigned short* __restrict__ Bt,
                                               unsigned short* __restrict__ Gb) {
  __shared__ __align__(16) short As[4096];   // swizzled k-chunk-major 128x32
  __shared__ __align__(16) short Bs[4096];
  const int tid = threadIdx.x;
  const int l = tid & 63, w = tid >> 6;
  const int wm = w & 1, wn = w >> 1;
  const int lm = l & 15, lq = l >> 4;
  const int bid = blockIdx.x;
  const int bm = bid & 255, bn = bid >> 8;   // grid 8192 = 256 x 32

  const int i0 = tid >> 2, kc0 = tid & 3;    // staging chunk (row, kchunk)
  const int la0 = (kc0 * 128 + (i0 ^ (kc0 << 2))) * 8;
  const int la1 = la0 + 512;                 // row+64 -> swizzled index +64 -> +512 shorts
  const unsigned short* Ap = A  + (size_t)(bm * 128 + i0) * 1024 + kc0 * 8;
  const unsigned short* Bp = Bt + (size_t)(bn * 128 + i0) * 1024 + kc0 * 8;

  f32x4 acc[4][4] = {};

  for (int kt = 0; kt < 32; ++kt) {
    const int k0 = kt * 32;
    bf16x8 av0 = *(const bf16x8*)(Ap + k0);
    bf16x8 av1 = *(const bf16x8*)(Ap + 64 * 1024 + k0);
    bf16x8 bv0 = *(const bf16x8*)(Bp + k0);
    bf16x8 bv1 = *(const bf16x8*)(Bp + 64 * 1024 + k0);
    __syncthreads();
    *(bf16x8*)(As + la0) = av0;
    *(bf16x8*)(As + la1) = av1;
    *(bf16x8*)(Bs + la0) = bv0;
    *(bf16x8*)(Bs + la1) = bv1;
    __syncthreads();

    bf16x8 af[4], bfv[4];
    #pragma unroll
    for (int mt = 0; mt < 4; ++mt) {
      const int i = wm * 64 + mt * 16 + lm;
      af[mt] = *(const bf16x8*)(As + (lq * 128 + (i ^ (lq << 2))) * 8);
    }
    #pragma unroll
    for (int nt = 0; nt < 4; ++nt) {
      const int i = wn * 64 + nt * 16 + lm;
      bfv[nt] = *(const bf16x8*)(Bs + (lq * 128 + (i ^ (lq << 2))) * 8);
    }
    #pragma unroll
    for (int mt = 0; mt < 4; ++mt)
      #pragma unroll
      for (int nt = 0; nt < 4; ++nt)
        acc[mt][nt] = __builtin_amdgcn_mfma_f32_16x16x32_bf16(af[mt], bfv[nt], acc[mt][nt], 0, 0, 0);
  }

  #pragma unroll
  for (int mt = 0; mt < 4; ++mt)
    #pragma unroll
    for (int nt = 0; nt < 4; ++nt) {
      const int col = bn * 128 + wn * 64 + nt * 16 + lm;
      const int r0  = bm * 128 + wm * 64 + mt * 16 + lq * 4;
      #pragma unroll
      for (int r = 0; r < 4; ++r)
        Gb[(size_t)(r0 + r) * 4096 + col] = f2bf(acc[mt][nt][r]);
    }
}

// ---- one pipeline slot: one step of one batch group ----
__device__ __forceinline__ void lstm_slot(
    const int t, const int grp, const int nh, const int jh,
    const int tid, const int l, const int w, const int lm, const int lq,
    const int b, const int j,
    const unsigned short* __restrict__ Gb,
    const bf16x8 (&vf)[8][4],
    const float (&bias_r)[4],
    float& c, float (&gp)[4],
    uint32_t* __restrict__ hb32,
    uint32_t* __restrict__ flags,
    float* __restrict__ out,
    float* gbuf,
    int& budget, bool& pend, const uint32_t*& pendPtr, uint32_t& pendVal) {
  const int gr = (grp << 4) + b;
  const uint32_t texp = (uint32_t)t;

  // prefetch next step's G slice (cacheable; drained by the spins' waitcnt)
  float gn[4];
  {
    const int t2 = t < 511 ? t + 1 : t;
    const size_t grow = ((size_t)(gr << 9) + t2) * 4096;
    #pragma unroll
    for (int gg = 0; gg < 4; ++gg) gn[gg] = bf2f(Gb[grow + (gg << 10) + jh + j]);
  }

  // --- flag hint spin. Carries the DEFERRED publish of the previous slot's
  //     flag: this spin's vmcnt(0) drains the previous slot's h store (same
  //     wave, program order), after which lane0 publishes. ---
  {
    const uint32_t* fwatch = flags + (((grp << 6) + l) << 2);
    u32x4 fq;
    do {
      asm volatile("global_load_dwordx4 %0, %1, off sc0 sc1\n\t"
                   "s_waitcnt vmcnt(0)"
                   : "=&v"(fq) : "v"(fwatch) : "memory");
      if (pend) {
        if (l == 0)
          asm volatile("global_store_dword %0, %1, off sc0 sc1"
                       :: "v"(pendPtr), "v"(pendVal) : "memory");
        pend = false;
      }
      const int ok = (fq[0] >= texp) & (fq[1] >= texp) & (fq[2] >= texp) & (fq[3] >= texp);
      if (__all(ok)) break;
      __builtin_amdgcn_s_sleep(2);
    } while (--budget > 0);
  }

  // --- spin-load tagged h fragments (cache-bypass) until tags == t ---
  const uint32_t* hp = hb32 + ((t & 1) << 16) + (((grp << 4) + lm) << 10) + (w << 8) + (lq << 3);
  u32x4 q0, q1, q2, q3, q4, q5, q6, q7, q8, q9, q10, q11, q12, q13, q14, q15;
  do {
    asm volatile(
        "global_load_dwordx4 %0, %16, off sc0 sc1\n\t"
        "global_load_dwordx4 %1, %16, off offset:16 sc0 sc1\n\t"
        "global_load_dwordx4 %2, %16, off offset:128 sc0 sc1\n\t"
        "global_load_dwordx4 %3, %16, off offset:144 sc0 sc1\n\t"
        "global_load_dwordx4 %4, %16, off offset:256 sc0 sc1\n\t"
        "global_load_dwordx4 %5, %16, off offset:272 sc0 sc1\n\t"
        "global_load_dwordx4 %6, %16, off offset:384 sc0 sc1\n\t"
        "global_load_dwordx4 %7, %16, off offset:400 sc0 sc1\n\t"
        "global_load_dwordx4 %8, %16, off offset:512 sc0 sc1\n\t"
        "global_load_dwordx4 %9, %16, off offset:528 sc0 sc1\n\t"
        "global_load_dwordx4 %10, %16, off offset:640 sc0 sc1\n\t"
        "global_load_dwordx4 %11, %16, off offset:656 sc0 sc1\n\t"
        "global_load_dwordx4 %12, %16, off offset:768 sc0 sc1\n\t"
        "global_load_dwordx4 %13, %16, off offset:784 sc0 sc1\n\t"
        "global_load_dwordx4 %14, %16, off offset:896 sc0 sc1\n\t"
        "global_load_dwordx4 %15, %16, off offset:912 sc0 sc1\n\t"
        "s_waitcnt vmcnt(0)"
        : "=&v"(q0), "=&v"(q1), "=&v"(q2), "=&v"(q3),
          "=&v"(q4), "=&v"(q5), "=&v"(q6), "=&v"(q7),
          "=&v"(q8), "=&v"(q9), "=&v"(q10), "=&v"(q11),
          "=&v"(q12), "=&v"(q13), "=&v"(q14), "=&v"(q15)
        : "v"(hp)
        : "memory");
    #define TC4(Q) ((Q[0] ^ texp) | (Q[1] ^ texp) | (Q[2] ^ texp) | (Q[3] ^ texp))
    const uint32_t dd = TC4(q0) | TC4(q1) | TC4(q2) | TC4(q3) |
                        TC4(q4) | TC4(q5) | TC4(q6) | TC4(q7) |
                        TC4(q8) | TC4(q9) | TC4(q10) | TC4(q11) |
                        TC4(q12) | TC4(q13) | TC4(q14) | TC4(q15);
    #undef TC4
    const int stale = (dd & 0xFFFFu) != 0;
    if (!__any(stale)) break;
    __builtin_amdgcn_s_sleep(2);
  } while (--budget > 0);

  // extract bf16 payloads (high 16 of each u32) into MFMA A-fragments
  bf16x8 a[8];
  #define MK(A, QA, QB) { u32x4 pa;                                     \
    pa[0] = __builtin_amdgcn_perm(QA[1], QA[0], 0x07060302u);           \
    pa[1] = __builtin_amdgcn_perm(QA[3], QA[2], 0x07060302u);           \
    pa[2] = __builtin_amdgcn_perm(QB[1], QB[0], 0x07060302u);           \
    pa[3] = __builtin_amdgcn_perm(QB[3], QB[2], 0x07060302u);           \
    A = __builtin_bit_cast(bf16x8, pa); }
  MK(a[0], q0, q1)  MK(a[1], q2, q3)  MK(a[2], q4, q5)  MK(a[3], q6, q7)
  MK(a[4], q8, q9)  MK(a[5], q10, q11) MK(a[6], q12, q13) MK(a[7], q14, q15)
  #undef MK

  f32x4 acc[4] = {};
  #pragma unroll
  for (int ks = 0; ks < 8; ++ks)
    #pragma unroll
    for (int gg = 0; gg < 4; ++gg)
      acc[gg] = __builtin_amdgcn_mfma_f32_16x16x32_bf16(a[ks], vf[ks][gg], acc[gg], 0, 0, 0);

  // partial (per-wave k-quarter) -> LDS for cross-wave reduction
  #pragma unroll
  for (int gg = 0; gg < 4; ++gg)
    #pragma unroll
    for (int r = 0; r < 4; ++r)
      gbuf[((w << 8) + ((lq << 2) + r) * 16 + lm) * 4 + gg] = acc[gg][r];

  // partials visible to all waves: LDS-only drain + raw barrier (no vmcnt!)
  asm volatile("s_waitcnt lgkmcnt(0)" ::: "memory");
  __builtin_amdgcn_sched_barrier(0);
  __builtin_amdgcn_s_barrier();
  __builtin_amdgcn_sched_barrier(0);

  f32x4 hv = *(const f32x4*)(gbuf + (tid << 2));
  hv += *(const f32x4*)(gbuf + ((256 + tid) << 2));
  hv += *(const f32x4*)(gbuf + ((512 + tid) << 2));
  hv += *(const f32x4*)(gbuf + ((768 + tid) << 2));

  const float pn = hv[0] + gp[0] + bias_r[0];
  const float pi = hv[1] + gp[1] + bias_r[1];
  const float pf = hv[2] + gp[2] + bias_r[2];
  const float po = hv[3] + gp[3] + bias_r[3];
  const float nn = tanhf_(pn);
  const float ii = sigf(pi);
  const float ff = sigf(pf);
  const float oo = sigf(po);
  c = c * ff + nn * ii;
  const float h = tanhf_(c) * oo;

  out[(size_t)gr * 524288 + ((size_t)t << 10) + jh + j] = h;

  // tagged write-through h store: payload + tag in one atomic dword.
  // NOT drained here — the next slot's flag-spin vmcnt(0) drains it, then
  // publishes this slot's flag (pend below).
  {
    const uint32_t* sp = hb32 + (((t + 1) & 1) << 16) + ((size_t)(gr << 10)) + jh + j;
    const uint32_t hw = (((uint32_t)f2bf(h)) << 16) | ((uint32_t)(t + 1) & 0xFFFFu);
    asm volatile("global_store_dword %0, %1, off sc0 sc1"
                 :: "v"(sp), "v"(hw) : "memory");
  }

  if (t == 511) {
    out[OUT_HF + (gr << 10) + jh + j] = h;
    out[OUT_CF + (gr << 10) + jh + j] = c;
  }
  #pragma unroll
  for (int gg = 0; gg < 4; ++gg) gp[gg] = gn[gg];

  // defer flag publish: per-wave flag word, published by next slot's spin
  pendPtr = flags + (((grp << 6) + nh) << 2) + w;
  pendVal = (uint32_t)(t + 1);
  pend = true;

  // protect gbuf for the next slot (reads done; LDS-only barrier)
  __builtin_amdgcn_sched_barrier(0);
  __builtin_amdgcn_s_barrier();
  __builtin_amdgcn_sched_barrier(0);
}

// ---------------- persistent recurrence (depth-2 pipelined) ----------------
__global__ void __launch_bounds__(256, 1) lstm_rec(
    const unsigned short* __restrict__ Gb,   // bf16 [32768][4096], row = b*512+t
    const float* __restrict__ V,             // fp32 [1024][4096]
    const float* __restrict__ Bias,          // fp32 [4096]
    const float* __restrict__ c0,            // fp32 [64][1024]
    uint32_t* __restrict__ hb32,             // u32 2x[64][1024]: bf16<<16 | tag
    uint32_t* __restrict__ flags,            // u32 [4][64][4]: per-(group,block,wave) step
    float* __restrict__ out) {
  __shared__ __align__(16) float gbuf[4096];  // [w][b16][j16][g4] (shared serially by slots)
  const int tid = threadIdx.x;
  const int l = tid & 63, w = tid >> 6;       // wave w owns k-quarter w
  const int lm = l & 15, lq = l >> 4;
  const int bid = blockIdx.x;                 // grid 128
  const int pr = bid >> 6;                    // pair: 0 -> groups {0,1}, 1 -> {2,3}
  const int g0 = pr << 1, g1 = g0 + 1;
  const int nh = bid & 63;                    // hidden tile
  const int jh = nh << 4;

  // stationary V fragments: vf[ks][gate], k = w*256 + ks*32 + lq*8 + jj, n = jh+lm
  bf16x8 vf[8][4];
  {
    const int col0 = jh + lm;
    #pragma unroll
    for (int ks = 0; ks < 8; ++ks) {
      const int kb = (w << 8) + (ks << 5) + (lq << 3);
      #pragma unroll
      for (int gg = 0; gg < 4; ++gg) {
        const size_t base = (size_t)kb * 4096 + (gg << 10) + col0;
        bf16x8 v;
        #pragma unroll
        for (int jj = 0; jj < 8; ++jj)
          v[jj] = (short)f2bf(V[base + (size_t)jj * 4096]);
        vf[ks][gg] = v;
      }
    }
  }

  // elementwise state: one cell (row b, col j) per thread, c stays in registers
  const int b  = tid >> 4;
  const int j  = tid & 15;
  const int gr0 = (g0 << 4) + b;
  const int gr1 = (g1 << 4) + b;
  float bias_r[4];
  #pragma unroll
  for (int gg = 0; gg < 4; ++gg) bias_r[gg] = Bias[(gg << 10) + jh + j];
  float cA = c0[(gr0 << 10) + jh + j];
  float cB = c0[(gr1 << 10) + jh + j];

  float gpA[4], gpB[4];
  {
    const size_t growA = (size_t)(gr0 << 9) * 4096;
    const size_t growB = (size_t)(gr1 << 9) * 4096;
    #pragma unroll
    for (int gg = 0; gg < 4; ++gg) {
      gpA[gg] = bf2f(Gb[growA + (gg << 10) + jh + j]);
      gpB[gg] = bf2f(Gb[growB + (gg << 10) + jh + j]);
    }
  }

  int budget = 20000000;  // hang-safety valve across the whole kernel
  bool pend = false;
  const uint32_t* pendPtr = nullptr;
  uint32_t pendVal = 0;

  for (int t = 0; t < 512; ++t) {
    lstm_slot(t, g0, nh, jh, tid, l, w, lm, lq, b, j,
              Gb, vf, bias_r, cA, gpA, hb32, flags, out, gbuf,
              budget, pend, pendPtr, pendVal);
    lstm_slot(t, g1, nh, jh, tid, l, w, lm, lq, b, j,
              Gb, vf, bias_r, cB, gpB, hb32, flags, out, gbuf,
              budget, pend, pendPtr, pendVal);
  }
}

extern "C" void kernel_launch(void* const* d_in, const int* in_sizes, int n_in,
                              void* d_out, int out_size, void* d_ws, size_t ws_size,
                              hipStream_t stream) {
  const float* x  = (const float*)d_in[0];
  const float* U  = (const float*)d_in[1];
  const float* V  = (const float*)d_in[2];
  const float* Bi = (const float*)d_in[3];
  const float* h0 = (const float*)d_in[4];
  const float* c0 = (const float*)d_in[5];
  float* out = (float*)d_out;
  char* ws = (char*)d_ws;

  unsigned short* Gb = (unsigned short*)(ws + WS_G);
  unsigned short* xb = (unsigned short*)(ws + WS_XB);
  unsigned short* ut = (unsigned short*)(ws + WS_UT);
  uint32_t* hb32     = (uint32_t*)(ws + WS_HB);
  uint32_t* flg      = (uint32_t*)(ws + WS_FL);

  convert_x  <<<32768, 256, 0, stream>>>(x, xb);
  transpose_u<<<dim3(16, 64), 256, 0, stream>>>(U, ut);
  gemm_xu    <<<8192, 256, 0, stream>>>(xb, ut, Gb);
  // init_h AFTER gemm_xu: hb32/flags alias xb's storage
  init_h     <<<256, 256, 0, stream>>>(h0, hb32, flg);
  lstm_rec   <<<128, 256, 0, stream>>>(Gb, V, Bi, c0, hb32, flg, out);
}

// Round 4
// 3942.878 us; speedup vs baseline: 1.1108x; 1.1108x over previous
//
#include <hip/hip_runtime.h>
#include <stdint.h>

// LSTM: B=64 S=512 IN=HID=1024, fp32 in/out.
// d_in: x(64,512,1024) U(1024,4096) V(1024,4096) B(4096) h0(64,1024) c0(64,1024)
// d_out: out(64,512,1024) ++ h_fin(64,1024) ++ c_fin(64,1024)
//
// G = x@U precomputed as one big bf16 MFMA GEMM. Persistent 256-block kernel
// runs the 512-step recurrence with V stationary in VGPRs as MFMA B-frags.
//
// Sync protocol history:
//  R3: flag-release raced (flag visible at MALL before write-through data).
//  R4: TAG-IN-DATA — h exchanged as u32 = bf16(h)<<16 | step_tag; readers
//      bulk-load (sc0 sc1) and re-pass until all tags match.
//  R5: divergent per-fragment retry — REGRESSED (serialized MALL RTs).
//  R6: flag-as-hint before bulk pass (2280us). Flag also provided
//      overwrite-safety: block publishes flag after __syncthreads => all its
//      waves' reads done => safe for peers to overwrite the read buffer.
//  R7: depth-2 pipeline — REGRESSED 65% (half CUs idle, extra hops/barriers
//      per step). Reverted. Lesson: hops are the currency.
//  R8: SENTINEL-IN-DATA. No flag array. Readers poll 8 sentinel dwords/wave
//      of the tagged h data itself: (a) readiness set = 1 dword per 64B
//      transaction the wave's bulk reads; (b) overwrite-safety set = the
//      sentinels proving every block's wave w*=nh>>4 (the unique reader wave
//      of this block's tile) finished its previous bulk (sentinel is issued
//      after that wave's compute => after its reads, program order). Writer:
//      tagged h store with NO drain/publish — the store is the signal. Bulk
//      tag-retry remains the data-readiness backstop. gbuf barriers are raw
//      s_barrier (LDS-only waits) so VMEM is never re-drained.

#define OUT_HF  33554432
#define OUT_CF  33619968

typedef __attribute__((ext_vector_type(8))) short bf16x8;
typedef __attribute__((ext_vector_type(4))) float f32x4;
typedef __attribute__((ext_vector_type(4))) unsigned short u16x4;
typedef __attribute__((ext_vector_type(4))) unsigned int u32x4;

// ---- ws layout (bytes) ----
#define WS_G    0                 // bf16 G[32768][4096]    268435456
#define WS_XB   268435456         // bf16 x  [32768][1024]   67108864 (dead after gemm)
#define WS_HB   268435456         // u32 hbuf[2][64][1024]     524288 (aliases XB; init_h runs after gemm)
#define WS_UT   335544320         // bf16 U^T[4096][1024]     8388608

__device__ __forceinline__ unsigned short f2bf(float f) {
  unsigned u = __float_as_uint(f);
  u += 0x7FFFu + ((u >> 16) & 1u);          // RNE
  return (unsigned short)(u >> 16);
}
__device__ __forceinline__ float bf2f(unsigned short b) {
  return __uint_as_float(((unsigned)b) << 16);
}
__device__ __forceinline__ float sigf(float x)   { return 1.0f / (1.0f + __expf(-x)); }
__device__ __forceinline__ float tanhf_(float x) { return 2.0f / (1.0f + __expf(-2.0f * x)) - 1.0f; }

// ---------------- x fp32 -> bf16 ----------------
__global__ void convert_x(const float* __restrict__ x, unsigned short* __restrict__ xb) {
  const int i = (blockIdx.x * 256 + threadIdx.x) * 4;   // grid 32768
  f32x4 v = *(const f32x4*)(x + i);
  u16x4 o;
  o[0] = f2bf(v[0]); o[1] = f2bf(v[1]); o[2] = f2bf(v[2]); o[3] = f2bf(v[3]);
  *(u16x4*)(xb + i) = o;
}

// ---------------- U fp32 (1024x4096) -> bf16 U^T (4096x1024) ----------------
__global__ void transpose_u(const float* __restrict__ U, unsigned short* __restrict__ ut) {
  __shared__ unsigned short t[64 * 65];
  const int kt = blockIdx.x;      // 16
  const int nt = blockIdx.y;      // 64
  const int tid = threadIdx.x;
  const int nn = tid & 63, kq = tid >> 6;
  #pragma unroll
  for (int i = 0; i < 16; ++i) {
    const int kk = kq * 16 + i;
    t[kk * 65 + nn] = f2bf(U[(size_t)(kt * 64 + kk) * 4096 + nt * 64 + nn]);
  }
  __syncthreads();
  const int kk2 = tid & 63, nq = tid >> 6;
  #pragma unroll
  for (int i = 0; i < 16; ++i) {
    const int nn2 = nq * 16 + i;
    ut[(size_t)(nt * 64 + nn2) * 1024 + kt * 64 + kk2] = t[kk2 * 65 + nn2];
  }
}

// ---------------- init: h0 -> tagged u32 buffer (coherence-point stores) ----
__global__ void init_h(const float* __restrict__ h0, uint32_t* __restrict__ hb32) {
  const int i = blockIdx.x * 256 + threadIdx.x;   // grid 256 -> 65536
  const uint32_t w0 = ((uint32_t)f2bf(h0[i])) << 16;   // tag 0
  const uint32_t w1 = 0xFFFFFFFFu;                     // tag 0xFFFF: never matches
  const uint32_t* p0 = hb32 + i;
  const uint32_t* p1 = hb32 + 65536 + i;
  asm volatile("global_store_dword %0, %2, off sc0 sc1\n\t"
               "global_store_dword %1, %3, off sc0 sc1"
               :: "v"(p0), "v"(p1), "v"(w0), "v"(w1) : "memory");
}

// ---------------- G = x @ U  (bf16 MFMA, 128x128x32 tiles) ----------------
__global__ void __launch_bounds__(256) gemm_xu(const unsigned short* __restrict__ A,
                                               const unsigned short* __restrict__ Bt,
                                               unsigned short* __restrict__ Gb) {
  __shared__ __align__(16) short As[4096];   // swizzled k-chunk-major 128x32
  __shared__ __align__(16) short Bs[4096];
  const int tid = threadIdx.x;
  const int l = tid & 63, w = tid >> 6;
  const int wm = w & 1, wn = w >> 1;
  const int lm = l & 15, lq = l >> 4;
  const int bid = blockIdx.x;
  const int bm = bid & 255, bn = bid >> 8;   // grid 8192 = 256 x 32

  const int i0 = tid >> 2, kc0 = tid & 3;    // staging chunk (row, kchunk)
  const int la0 = (kc0 * 128 + (i0 ^ (kc0 << 2))) * 8;
  const int la1 = la0 + 512;                 // row+64 -> swizzled index +64 -> +512 shorts
  const unsigned short* Ap = A  + (size_t)(bm * 128 + i0) * 1024 + kc0 * 8;
  const unsigned short* Bp = Bt + (size_t)(bn * 128 + i0) * 1024 + kc0 * 8;

  f32x4 acc[4][4] = {};

  for (int kt = 0; kt < 32; ++kt) {
    const int k0 = kt * 32;
    bf16x8 av0 = *(const bf16x8*)(Ap + k0);
    bf16x8 av1 = *(const bf16x8*)(Ap + 64 * 1024 + k0);
    bf16x8 bv0 = *(const bf16x8*)(Bp + k0);
    bf16x8 bv1 = *(const bf16x8*)(Bp + 64 * 1024 + k0);
    __syncthreads();
    *(bf16x8*)(As + la0) = av0;
    *(bf16x8*)(As + la1) = av1;
    *(bf16x8*)(Bs + la0) = bv0;
    *(bf16x8*)(Bs + la1) = bv1;
    __syncthreads();

    bf16x8 af[4], bfv[4];
    #pragma unroll
    for (int mt = 0; mt < 4; ++mt) {
      const int i = wm * 64 + mt * 16 + lm;
      af[mt] = *(const bf16x8*)(As + (lq * 128 + (i ^ (lq << 2))) * 8);
    }
    #pragma unroll
    for (int nt = 0; nt < 4; ++nt) {
      const int i = wn * 64 + nt * 16 + lm;
      bfv[nt] = *(const bf16x8*)(Bs + (lq * 128 + (i ^ (lq << 2))) * 8);
    }
    #pragma unroll
    for (int mt = 0; mt < 4; ++mt)
      #pragma unroll
      for (int nt = 0; nt < 4; ++nt)
        acc[mt][nt] = __builtin_amdgcn_mfma_f32_16x16x32_bf16(af[mt], bfv[nt], acc[mt][nt], 0, 0, 0);
  }

  #pragma unroll
  for (int mt = 0; mt < 4; ++mt)
    #pragma unroll
    for (int nt = 0; nt < 4; ++nt) {
      const int col = bn * 128 + wn * 64 + nt * 16 + lm;
      const int r0  = bm * 128 + wm * 64 + mt * 16 + lq * 4;
      #pragma unroll
      for (int r = 0; r < 4; ++r)
        Gb[(size_t)(r0 + r) * 4096 + col] = f2bf(acc[mt][nt][r]);
    }
}

// ---------------- persistent recurrence (sentinel-in-data sync) ------------
__global__ void __launch_bounds__(256, 1) lstm_rec(
    const unsigned short* __restrict__ Gb,   // bf16 [32768][4096], row = b*512+t
    const float* __restrict__ V,             // fp32 [1024][4096]
    const float* __restrict__ Bias,          // fp32 [4096]
    const float* __restrict__ c0,            // fp32 [64][1024]
    uint32_t* __restrict__ hb32,             // u32 2x[64][1024]: bf16<<16 | tag
    float* __restrict__ out) {
  __shared__ __align__(16) float gbuf[4096];  // [w][b16][j16][g4]
  const int tid = threadIdx.x;
  const int l = tid & 63, w = tid >> 6;       // wave w owns k-quarter w
  const int lm = l & 15, lq = l >> 4;
  const int bid = blockIdx.x;
  const int mb = bid & 3;                     // batch group (independent recurrences)
  const int nh = bid >> 2;                    // hidden tile
  const int jh = nh << 4;
  const int wstar = nh >> 4;                  // the wave index (in every block) that reads our tile

  // stationary V fragments: vf[ks][gate], k = w*256 + ks*32 + lq*8 + jj, n = jh+lm
  bf16x8 vf[8][4];
  {
    const int col0 = jh + lm;
    #pragma unroll
    for (int ks = 0; ks < 8; ++ks) {
      const int kb = (w << 8) + (ks << 5) + (lq << 3);
      #pragma unroll
      for (int g = 0; g < 4; ++g) {
        const size_t base = (size_t)kb * 4096 + (g << 10) + col0;
        bf16x8 v;
        #pragma unroll
        for (int jj = 0; jj < 8; ++jj)
          v[jj] = (short)f2bf(V[base + (size_t)jj * 4096]);
        vf[ks][g] = v;
      }
    }
  }

  // elementwise state: one cell (b, j) per thread, c stays in a register
  const int b  = tid >> 4;
  const int j  = tid & 15;
  const int gr = (mb << 4) + b;
  float bias_r[4];
  #pragma unroll
  for (int g = 0; g < 4; ++g) bias_r[g] = Bias[(g << 10) + jh + j];
  float c = c0[(gr << 10) + jh + j];

  const int abase32 = ((mb << 4) + lm) * 1024 + (w << 8) + (lq << 3);  // u32 elems (bulk)
  // sentinel offsets (u32 elems):
  //  readiness: 1 dword per 64B transaction this wave's bulk reads.
  //    lane l: row = l&15, tiles (w*16 + (l>>4)*4 + p), p=0..3 (+64B apart)
  const int poll_r = (((mb << 4) + lm) << 10) + (((w << 4) + (lq << 2)) << 4);
  //  overwrite-safety: every block's wave wstar finished its previous bulk.
  //    lane l: row = wstar*4 + (l>>4), tiles ((l&15)*4 + p), p=0..3
  const int poll_o = (((mb << 4) + (wstar << 2) + lq) << 10) + (lm << 6);

  float gp[4], gn[4];
  {
    const size_t grow = (size_t)(gr << 9) * 4096;
    #pragma unroll
    for (int g = 0; g < 4; ++g) gp[g] = bf2f(Gb[grow + (g << 10) + jh + j]);
  }

  int budget = 20000000;  // hang-safety valve across the whole kernel

  for (int t = 0; t < 512; ++t) {
    // prefetch next step's G slice first (cached; drained by the spins' waitcnt)
    {
      const int t2 = t < 511 ? t + 1 : t;
      const size_t grow = ((size_t)(gr << 9) + t2) * 4096;
      #pragma unroll
      for (int g = 0; g < 4; ++g) gn[g] = bf2f(Gb[grow + (g << 10) + jh + j]);
    }

    const uint32_t texp = (uint32_t)t;
    const uint32_t* bufb = hb32 + ((t & 1) << 16);

    // --- sentinel poll: 8 dwords/lane of the tagged h data itself.
    //     Breaks only when (a) this wave's bulk set is ready AND (b) all
    //     peers' wave-wstar reads of the buffer we'll overwrite are done. ---
    {
      const uint32_t* pr = bufb + poll_r;
      const uint32_t* po = bufb + poll_o;
      uint32_t r0, r1, r2, r3, o0, o1, o2, o3;
      do {
        asm volatile(
            "global_load_dword %0, %8, off sc0 sc1\n\t"
            "global_load_dword %1, %8, off offset:64 sc0 sc1\n\t"
            "global_load_dword %2, %8, off offset:128 sc0 sc1\n\t"
            "global_load_dword %3, %8, off offset:192 sc0 sc1\n\t"
            "global_load_dword %4, %9, off sc0 sc1\n\t"
            "global_load_dword %5, %9, off offset:64 sc0 sc1\n\t"
            "global_load_dword %6, %9, off offset:128 sc0 sc1\n\t"
            "global_load_dword %7, %9, off offset:192 sc0 sc1\n\t"
            "s_waitcnt vmcnt(0)"
            : "=&v"(r0), "=&v"(r1), "=&v"(r2), "=&v"(r3),
              "=&v"(o0), "=&v"(o1), "=&v"(o2), "=&v"(o3)
            : "v"(pr), "v"(po)
            : "memory");
        const uint32_t dd = (r0 ^ texp) | (r1 ^ texp) | (r2 ^ texp) | (r3 ^ texp) |
                            (o0 ^ texp) | (o1 ^ texp) | (o2 ^ texp) | (o3 ^ texp);
        const int stale = (dd & 0xFFFFu) != 0;
        if (!__any(stale)) break;
        __builtin_amdgcn_s_sleep(2);
      } while (--budget > 0);
    }

    // --- bulk-load tagged h fragments (cache-bypass); tag-retry backstop ---
    const uint32_t* hp = bufb + abase32;
    u32x4 q0, q1, q2, q3, q4, q5, q6, q7, q8, q9, q10, q11, q12, q13, q14, q15;
    do {
      asm volatile(
          "global_load_dwordx4 %0, %16, off sc0 sc1\n\t"
          "global_load_dwordx4 %1, %16, off offset:16 sc0 sc1\n\t"
          "global_load_dwordx4 %2, %16, off offset:128 sc0 sc1\n\t"
          "global_load_dwordx4 %3, %16, off offset:144 sc0 sc1\n\t"
          "global_load_dwordx4 %4, %16, off offset:256 sc0 sc1\n\t"
          "global_load_dwordx4 %5, %16, off offset:272 sc0 sc1\n\t"
          "global_load_dwordx4 %6, %16, off offset:384 sc0 sc1\n\t"
          "global_load_dwordx4 %7, %16, off offset:400 sc0 sc1\n\t"
          "global_load_dwordx4 %8, %16, off offset:512 sc0 sc1\n\t"
          "global_load_dwordx4 %9, %16, off offset:528 sc0 sc1\n\t"
          "global_load_dwordx4 %10, %16, off offset:640 sc0 sc1\n\t"
          "global_load_dwordx4 %11, %16, off offset:656 sc0 sc1\n\t"
          "global_load_dwordx4 %12, %16, off offset:768 sc0 sc1\n\t"
          "global_load_dwordx4 %13, %16, off offset:784 sc0 sc1\n\t"
          "global_load_dwordx4 %14, %16, off offset:896 sc0 sc1\n\t"
          "global_load_dwordx4 %15, %16, off offset:912 sc0 sc1\n\t"
          "s_waitcnt vmcnt(0)"
          : "=&v"(q0), "=&v"(q1), "=&v"(q2), "=&v"(q3),
            "=&v"(q4), "=&v"(q5), "=&v"(q6), "=&v"(q7),
            "=&v"(q8), "=&v"(q9), "=&v"(q10), "=&v"(q11),
            "=&v"(q12), "=&v"(q13), "=&v"(q14), "=&v"(q15)
          : "v"(hp)
          : "memory");
      #define TC4(Q) ((Q[0] ^ texp) | (Q[1] ^ texp) | (Q[2] ^ texp) | (Q[3] ^ texp))
      const uint32_t dd = TC4(q0) | TC4(q1) | TC4(q2) | TC4(q3) |
                          TC4(q4) | TC4(q5) | TC4(q6) | TC4(q7) |
                          TC4(q8) | TC4(q9) | TC4(q10) | TC4(q11) |
                          TC4(q12) | TC4(q13) | TC4(q14) | TC4(q15);
      #undef TC4
      const int stale = (dd & 0xFFFFu) != 0;
      if (!__any(stale)) break;
      __builtin_amdgcn_s_sleep(2);
    } while (--budget > 0);

    // extract bf16 payloads (high 16 of each u32) into MFMA A-fragments
    bf16x8 a[8];
    #define MK(A, QA, QB) { u32x4 pa;                                     \
      pa[0] = __builtin_amdgcn_perm(QA[1], QA[0], 0x07060302u);           \
      pa[1] = __builtin_amdgcn_perm(QA[3], QA[2], 0x07060302u);           \
      pa[2] = __builtin_amdgcn_perm(QB[1], QB[0], 0x07060302u);           \
      pa[3] = __builtin_amdgcn_perm(QB[3], QB[2], 0x07060302u);           \
      A = __builtin_bit_cast(bf16x8, pa); }
    MK(a[0], q0, q1)  MK(a[1], q2, q3)  MK(a[2], q4, q5)  MK(a[3], q6, q7)
    MK(a[4], q8, q9)  MK(a[5], q10, q11) MK(a[6], q12, q13) MK(a[7], q14, q15)
    #undef MK

    f32x4 acc[4] = {};
    #pragma unroll
    for (int ks = 0; ks < 8; ++ks)
      #pragma unroll
      for (int g = 0; g < 4; ++g)
        acc[g] = __builtin_amdgcn_mfma_f32_16x16x32_bf16(a[ks], vf[ks][g], acc[g], 0, 0, 0);

    // partial (per-wave k-quarter) -> LDS for cross-wave reduction
    #pragma unroll
    for (int g = 0; g < 4; ++g)
      #pragma unroll
      for (int r = 0; r < 4; ++r)
        gbuf[((w << 8) + ((lq << 2) + r) * 16 + lm) * 4 + g] = acc[g][r];

    // LDS-only visibility barrier (raw: no vmcnt drain of h/out stores)
    asm volatile("s_waitcnt lgkmcnt(0)" ::: "memory");
    __builtin_amdgcn_sched_barrier(0);
    __builtin_amdgcn_s_barrier();
    __builtin_amdgcn_sched_barrier(0);

    f32x4 hv = *(const f32x4*)(gbuf + (tid << 2));
    hv += *(const f32x4*)(gbuf + ((256 + tid) << 2));
    hv += *(const f32x4*)(gbuf + ((512 + tid) << 2));
    hv += *(const f32x4*)(gbuf + ((768 + tid) << 2));

    const float pn = hv[0] + gp[0] + bias_r[0];
    const float pi = hv[1] + gp[1] + bias_r[1];
    const float pf = hv[2] + gp[2] + bias_r[2];
    const float po = hv[3] + gp[3] + bias_r[3];
    const float nn = tanhf_(pn);
    const float ii = sigf(pi);
    const float ff = sigf(pf);
    const float oo = sigf(po);
    c = c * ff + nn * ii;
    const float h = tanhf_(c) * oo;

    // tagged write-through h store: payload + tag in one atomic dword.
    // NO drain, NO publish — this store is the sentinel peers poll.
    {
      const uint32_t* sp = hb32 + (((t + 1) & 1) << 16) + (gr << 10) + jh + j;
      const uint32_t hw = (((uint32_t)f2bf(h)) << 16) | ((uint32_t)(t + 1) & 0xFFFFu);
      asm volatile("global_store_dword %0, %1, off sc0 sc1"
                   :: "v"(sp), "v"(hw) : "memory");
    }

    out[(size_t)gr * 524288 + ((size_t)t << 10) + jh + j] = h;
    if (t == 511) {
      out[OUT_HF + (gr << 10) + jh + j] = h;
      out[OUT_CF + (gr << 10) + jh + j] = c;
    }
    #pragma unroll
    for (int g = 0; g < 4; ++g) gp[g] = gn[g];

    // protect gbuf for next iteration (reads consumed into hv; raw barrier)
    __builtin_amdgcn_sched_barrier(0);
    __builtin_amdgcn_s_barrier();
    __builtin_amdgcn_sched_barrier(0);
  }
}

extern "C" void kernel_launch(void* const* d_in, const int* in_sizes, int n_in,
                              void* d_out, int out_size, void* d_ws, size_t ws_size,
                              hipStream_t stream) {
  const float* x  = (const float*)d_in[0];
  const float* U  = (const float*)d_in[1];
  const float* V  = (const float*)d_in[2];
  const float* Bi = (const float*)d_in[3];
  const float* h0 = (const float*)d_in[4];
  const float* c0 = (const float*)d_in[5];
  float* out = (float*)d_out;
  char* ws = (char*)d_ws;

  unsigned short* Gb = (unsigned short*)(ws + WS_G);
  unsigned short* xb = (unsigned short*)(ws + WS_XB);
  unsigned short* ut = (unsigned short*)(ws + WS_UT);
  uint32_t* hb32     = (uint32_t*)(ws + WS_HB);

  convert_x  <<<32768, 256, 0, stream>>>(x, xb);
  transpose_u<<<dim3(16, 64), 256, 0, stream>>>(U, ut);
  gemm_xu    <<<8192, 256, 0, stream>>>(xb, ut, Gb);
  // init_h AFTER gemm_xu: hb32 aliases xb's storage
  init_h     <<<256, 256, 0, stream>>>(h0, hb32);
  lstm_rec   <<<256, 256, 0, stream>>>(Gb, V, Bi, c0, hb32, out);
}

// Round 5
// 2605.359 us; speedup vs baseline: 1.6811x; 1.5134x over previous
//
#include <hip/hip_runtime.h>
#include <stdint.h>

// LSTM: B=64 S=512 IN=HID=1024, fp32 in/out.
// d_in: x(64,512,1024) U(1024,4096) V(1024,4096) B(4096) h0(64,1024) c0(64,1024)
// d_out: out(64,512,1024) ++ h_fin(64,1024) ++ c_fin(64,1024)
//
// G = x@U precomputed as one big bf16 MFMA GEMM. Persistent 256-block kernel
// runs the 512-step recurrence with V stationary in VGPRs as MFMA B-frags.
//
// Sync protocol history:
//  R3: flag-release raced (flag visible at MALL before write-through h data).
//  R4: TAG-IN-DATA — h exchanged as u32 = bf16(h)<<16 | step_tag; readers
//      bulk-load (sc0 sc1) and re-pass until all tags match. 2429us.
//  R5: divergent per-fragment retry — REGRESSED (serialized MALL RTs). 2577.
//  R6: flag-as-hint spin before the bulk pass. BEST so far: 2280us.
//  R7: depth-2 pipeline — REGRESSED 65% (half CUs idle, more hops). 3775.
//  R8: sentinel-in-data — REGRESSED (scattered polls added MALL load). 3403.
//  R9: BW attack. Evidence R4-R8: the ONE mandatory broadcast pass/step is
//      MALL-BW-bound (~16MB/step at ~3.7TB/s ≈ 4us/step). Broadcast bytes =
//      (1024/jt)*256KB, independent of group rows. Go jt=32 (32 cols/block),
//      groups of 8 rows: 8 groups x 32 jtiles = 256 blocks x 512 threads
//      (8 waves, K=128/wave keeps V-frags at 128 VGPR). Bulk 64->32KB/block,
//      16->8 MB/step. 8-row A-frags: lane pairs (l, l^8) load unique half-K
//      and exchange via ds_swizzle (no duplicate MALL requests). Sync = R6's
//      flag-hint + tag backstop, 32 writer flags/group.

#define OUT_HF  33554432
#define OUT_CF  33619968

typedef __attribute__((ext_vector_type(8))) short bf16x8;
typedef __attribute__((ext_vector_type(4))) float f32x4;
typedef __attribute__((ext_vector_type(4))) unsigned short u16x4;
typedef __attribute__((ext_vector_type(4))) unsigned int u32x4;

// ---- ws layout (bytes) ----
#define WS_G    0                 // bf16 G[32768][4096]    268435456
#define WS_XB   268435456         // bf16 x  [32768][1024]   67108864 (dead after gemm)
#define WS_HB   268435456         // u32 hbuf[2][64][1024]     524288 (aliases XB; init_h runs after gemm)
#define WS_FL   268959744         // u32 flags[8][32][16]        16384 (aliases XB too)
#define WS_UT   335544320         // bf16 U^T[4096][1024]     8388608

__device__ __forceinline__ unsigned short f2bf(float f) {
  unsigned u = __float_as_uint(f);
  u += 0x7FFFu + ((u >> 16) & 1u);          // RNE
  return (unsigned short)(u >> 16);
}
__device__ __forceinline__ float bf2f(unsigned short b) {
  return __uint_as_float(((unsigned)b) << 16);
}
__device__ __forceinline__ float sigf(float x)   { return 1.0f / (1.0f + __expf(-x)); }
__device__ __forceinline__ float tanhf_(float x) { return 2.0f / (1.0f + __expf(-2.0f * x)) - 1.0f; }

// ---------------- x fp32 -> bf16 ----------------
__global__ void convert_x(const float* __restrict__ x, unsigned short* __restrict__ xb) {
  const int i = (blockIdx.x * 256 + threadIdx.x) * 4;   // grid 32768
  f32x4 v = *(const f32x4*)(x + i);
  u16x4 o;
  o[0] = f2bf(v[0]); o[1] = f2bf(v[1]); o[2] = f2bf(v[2]); o[3] = f2bf(v[3]);
  *(u16x4*)(xb + i) = o;
}

// ---------------- U fp32 (1024x4096) -> bf16 U^T (4096x1024) ----------------
__global__ void transpose_u(const float* __restrict__ U, unsigned short* __restrict__ ut) {
  __shared__ unsigned short t[64 * 65];
  const int kt = blockIdx.x;      // 16
  const int nt = blockIdx.y;      // 64
  const int tid = threadIdx.x;
  const int nn = tid & 63, kq = tid >> 6;
  #pragma unroll
  for (int i = 0; i < 16; ++i) {
    const int kk = kq * 16 + i;
    t[kk * 65 + nn] = f2bf(U[(size_t)(kt * 64 + kk) * 4096 + nt * 64 + nn]);
  }
  __syncthreads();
  const int kk2 = tid & 63, nq = tid >> 6;
  #pragma unroll
  for (int i = 0; i < 16; ++i) {
    const int nn2 = nq * 16 + i;
    ut[(size_t)(nt * 64 + nn2) * 1024 + kt * 64 + kk2] = t[kk2 * 65 + nn2];
  }
}

// ---------------- init: h0 -> tagged u32 buffer + zero flags ----------------
__global__ void init_h(const float* __restrict__ h0, uint32_t* __restrict__ hb32,
                       uint32_t* __restrict__ flags) {
  const int i = blockIdx.x * 256 + threadIdx.x;   // grid 256 -> 65536
  const uint32_t w0 = ((uint32_t)f2bf(h0[i])) << 16;   // tag 0
  const uint32_t w1 = 0xFFFFFFFFu;                     // tag 0xFFFF: never matches
  const uint32_t* p0 = hb32 + i;
  const uint32_t* p1 = hb32 + 65536 + i;
  asm volatile("global_store_dword %0, %2, off sc0 sc1\n\t"
               "global_store_dword %1, %3, off sc0 sc1"
               :: "v"(p0), "v"(p1), "v"(w0), "v"(w1) : "memory");
  if (i < 4096) {   // flags[8][32][16] = 0 : "step-0 h is ready" (matches tag-0 data)
    const uint32_t* fp = flags + i;
    const uint32_t z = 0u;
    asm volatile("global_store_dword %0, %1, off sc0 sc1"
                 :: "v"(fp), "v"(z) : "memory");
  }
}

// ---------------- G = x @ U  (bf16 MFMA, 128x128x32 tiles) ----------------
__global__ void __launch_bounds__(256) gemm_xu(const unsigned short* __restrict__ A,
                                               const unsigned short* __restrict__ Bt,
                                               unsigned short* __restrict__ Gb) {
  __shared__ __align__(16) short As[4096];   // swizzled k-chunk-major 128x32
  __shared__ __align__(16) short Bs[4096];
  const int tid = threadIdx.x;
  const int l = tid & 63, w = tid >> 6;
  const int wm = w & 1, wn = w >> 1;
  const int lm = l & 15, lq = l >> 4;
  const int bid = blockIdx.x;
  const int bm = bid & 255, bn = bid >> 8;   // grid 8192 = 256 x 32

  const int i0 = tid >> 2, kc0 = tid & 3;    // staging chunk (row, kchunk)
  const int la0 = (kc0 * 128 + (i0 ^ (kc0 << 2))) * 8;
  const int la1 = la0 + 512;                 // row+64 -> swizzled index +64 -> +512 shorts
  const unsigned short* Ap = A  + (size_t)(bm * 128 + i0) * 1024 + kc0 * 8;
  const unsigned short* Bp = Bt + (size_t)(bn * 128 + i0) * 1024 + kc0 * 8;

  f32x4 acc[4][4] = {};

  for (int kt = 0; kt < 32; ++kt) {
    const int k0 = kt * 32;
    bf16x8 av0 = *(const bf16x8*)(Ap + k0);
    bf16x8 av1 = *(const bf16x8*)(Ap + 64 * 1024 + k0);
    bf16x8 bv0 = *(const bf16x8*)(Bp + k0);
    bf16x8 bv1 = *(const bf16x8*)(Bp + 64 * 1024 + k0);
    __syncthreads();
    *(bf16x8*)(As + la0) = av0;
    *(bf16x8*)(As + la1) = av1;
    *(bf16x8*)(Bs + la0) = bv0;
    *(bf16x8*)(Bs + la1) = bv1;
    __syncthreads();

    bf16x8 af[4], bfv[4];
    #pragma unroll
    for (int mt = 0; mt < 4; ++mt) {
      const int i = wm * 64 + mt * 16 + lm;
      af[mt] = *(const bf16x8*)(As + (lq * 128 + (i ^ (lq << 2))) * 8);
    }
    #pragma unroll
    for (int nt = 0; nt < 4; ++nt) {
      const int i = wn * 64 + nt * 16 + lm;
      bfv[nt] = *(const bf16x8*)(Bs + (lq * 128 + (i ^ (lq << 2))) * 8);
    }
    #pragma unroll
    for (int mt = 0; mt < 4; ++mt)
      #pragma unroll
      for (int nt = 0; nt < 4; ++nt)
        acc[mt][nt] = __builtin_amdgcn_mfma_f32_16x16x32_bf16(af[mt], bfv[nt], acc[mt][nt], 0, 0, 0);
  }

  #pragma unroll
  for (int mt = 0; mt < 4; ++mt)
    #pragma unroll
    for (int nt = 0; nt < 4; ++nt) {
      const int col = bn * 128 + wn * 64 + nt * 16 + lm;
      const int r0  = bm * 128 + wm * 64 + mt * 16 + lq * 4;
      #pragma unroll
      for (int r = 0; r < 4; ++r)
        Gb[(size_t)(r0 + r) * 4096 + col] = f2bf(acc[mt][nt][r]);
    }
}

// ---------------- persistent recurrence (flag-hint + tag-in-data) ----------
// grid 256 x 512 threads. Block (mb = bid&7 group of 8 rows, nh = bid>>3 of
// 32 j-tiles). Wave w owns K-window [w*128,(w+1)*128).
__global__ void __launch_bounds__(512, 1) lstm_rec(
    const unsigned short* __restrict__ Gb,   // bf16 [32768][4096], row = b*512+t
    const float* __restrict__ V,             // fp32 [1024][4096]
    const float* __restrict__ Bias,          // fp32 [4096]
    const float* __restrict__ c0,            // fp32 [64][1024]
    uint32_t* __restrict__ hb32,             // u32 2x[64][1024]: bf16<<16 | tag
    uint32_t* __restrict__ flags,            // u32 [8][32][16]: per-block step counter
    float* __restrict__ out) {
  __shared__ __align__(16) float gbuf[8192];  // [w8][b8][c32][g4]
  const int tid = threadIdx.x;
  const int l = tid & 63, w = tid >> 6;       // 8 waves
  const int lm = l & 15;                      // MFMA col lane
  const int kq = l >> 4;                      // k-subslice 0..3
  const int bid = blockIdx.x;
  const int mb = bid & 7;                     // batch group (8 rows); groups XCD-local
  const int nh = bid >> 3;                    // j-tile 0..31
  const int jh = nh << 5;                     // 32 cols

  // stationary V fragments: vf[ks][gate][ct]; k = w*128+ks*32+kq*8+jj,
  // col = jh + ct*16 + lm   (128 VGPR)
  bf16x8 vf[4][4][2];
  {
    #pragma unroll
    for (int ks = 0; ks < 4; ++ks) {
      const int kb = (w << 7) + (ks << 5) + (kq << 3);
      #pragma unroll
      for (int g = 0; g < 4; ++g)
        #pragma unroll
        for (int ct = 0; ct < 2; ++ct) {
          const size_t base = (size_t)kb * 4096 + (g << 10) + jh + (ct << 4) + lm;
          bf16x8 v;
          #pragma unroll
          for (int jj = 0; jj < 8; ++jj)
            v[jj] = (short)f2bf(V[base + (size_t)jj * 4096]);
          vf[ks][g][ct] = v;
        }
    }
  }

  // cell ownership: waves 0-3 (tid<256) hold the 8x32 cells, one per thread
  const int b  = (tid >> 5) & 7;
  const int cc = tid & 31;
  const int gr = (mb << 3) + b;
  const bool cellown = tid < 256;             // wave-uniform
  float bias_r[4];
  #pragma unroll
  for (int g = 0; g < 4; ++g) bias_r[g] = Bias[(g << 10) + jh + cc];
  float c = cellown ? c0[(gr << 10) + jh + cc] : 0.0f;

  // bulk: lane pairs (l, l^8) split the K-window halves; unique addresses.
  // row = l&7, half = (l>>3)&1 (ks01 vs ks23), kq = l>>4.
  const int abase32 = ((mb << 3) + (l & 7)) * 1024 + (w << 7) + (((l >> 3) & 1) << 6) + (kq << 3);
  const bool hi = (l & 8) != 0;

  const uint32_t* fwatch = flags + (((mb << 5) + (l & 31)) << 4);  // 32 writer blocks
  const uint32_t* fmine  = flags + (((mb << 5) + nh) << 4);

  float gp[4], gn[4];
  if (cellown) {
    const size_t grow = (size_t)(gr << 9) * 4096;
    #pragma unroll
    for (int g = 0; g < 4; ++g) gp[g] = bf2f(Gb[grow + (g << 10) + jh + cc]);
  }

  int budget = 20000000;  // hang-safety valve across the whole kernel

  for (int t = 0; t < 512; ++t) {
    // prefetch next step's G slice (cached; drained by the spins' waitcnt)
    if (cellown) {
      const int t2 = t < 511 ? t + 1 : t;
      const size_t grow = ((size_t)(gr << 9) + t2) * 4096;
      #pragma unroll
      for (int g = 0; g < 4; ++g) gn[g] = bf2f(Gb[grow + (g << 10) + jh + cc]);
    }

    const uint32_t texp = (uint32_t)t;
    const uint32_t* bufb = hb32 + ((t & 1) << 16);

    // --- flag hint: spin on the 32 writer flags of this group (hint only) ---
    {
      uint32_t fv;
      do {
        asm volatile("global_load_dword %0, %1, off sc0 sc1\n\t"
                     "s_waitcnt vmcnt(0)"
                     : "=v"(fv) : "v"(fwatch) : "memory");
        if (__all(fv >= texp)) break;
        __builtin_amdgcn_s_sleep(2);
      } while (--budget > 0);
    }

    // --- bulk-load tagged h (cache-bypass): 4 dwordx4/lane, unique addrs;
    //     tag-retry backstop ---
    const uint32_t* hp = bufb + abase32;
    u32x4 r0, r1, r2, r3;
    do {
      asm volatile(
          "global_load_dwordx4 %0, %4, off sc0 sc1\n\t"
          "global_load_dwordx4 %1, %4, off offset:16 sc0 sc1\n\t"
          "global_load_dwordx4 %2, %4, off offset:128 sc0 sc1\n\t"
          "global_load_dwordx4 %3, %4, off offset:144 sc0 sc1\n\t"
          "s_waitcnt vmcnt(0)"
          : "=&v"(r0), "=&v"(r1), "=&v"(r2), "=&v"(r3)
          : "v"(hp)
          : "memory");
      #define TC4(Q) ((Q[0] ^ texp) | (Q[1] ^ texp) | (Q[2] ^ texp) | (Q[3] ^ texp))
      const uint32_t dd = TC4(r0) | TC4(r1) | TC4(r2) | TC4(r3);
      #undef TC4
      const int stale = (dd & 0xFFFFu) != 0;
      if (!__any(stale)) break;
      __builtin_amdgcn_s_sleep(2);
    } while (--budget > 0);

    // --- pair-exchange: lane l gets partner l^8's half via ds_swizzle ---
    u32x4 s0, s1, s2, s3;
    #define SWZ(D, S) { \
      D[0] = (unsigned)__builtin_amdgcn_ds_swizzle((int)S[0], 0x201F); \
      D[1] = (unsigned)__builtin_amdgcn_ds_swizzle((int)S[1], 0x201F); \
      D[2] = (unsigned)__builtin_amdgcn_ds_swizzle((int)S[2], 0x201F); \
      D[3] = (unsigned)__builtin_amdgcn_ds_swizzle((int)S[3], 0x201F); }
    SWZ(s0, r0) SWZ(s1, r1) SWZ(s2, r2) SWZ(s3, r3)
    #undef SWZ
    u32x4 qa0 = hi ? s0 : r0, qa1 = hi ? s1 : r1;   // ks0 words 0-7
    u32x4 qa2 = hi ? s2 : r2, qa3 = hi ? s3 : r3;   // ks1
    u32x4 qb0 = hi ? r0 : s0, qb1 = hi ? r1 : s1;   // ks2
    u32x4 qb2 = hi ? r2 : s2, qb3 = hi ? r3 : s3;   // ks3

    // extract bf16 payloads (high 16 of each u32) into MFMA A-fragments
    bf16x8 a0, a1, a2, a3;
    #define MK(A, QA, QB) { u32x4 pa;                                     \
      pa[0] = __builtin_amdgcn_perm(QA[1], QA[0], 0x07060302u);           \
      pa[1] = __builtin_amdgcn_perm(QA[3], QA[2], 0x07060302u);           \
      pa[2] = __builtin_amdgcn_perm(QB[1], QB[0], 0x07060302u);           \
      pa[3] = __builtin_amdgcn_perm(QB[3], QB[2], 0x07060302u);           \
      A = __builtin_bit_cast(bf16x8, pa); }
    MK(a0, qa0, qa1)  MK(a1, qa2, qa3)  MK(a2, qb0, qb1)  MK(a3, qb2, qb3)
    #undef MK

    // MFMA: A rows 0-15 = duplicated 8 batch rows; out rows 8-15 discarded
    f32x4 acc[2][4] = {};
    #define DOKS(A, KS)                                                               \
      _Pragma("unroll")                                                               \
      for (int g = 0; g < 4; ++g) {                                                   \
        acc[0][g] = __builtin_amdgcn_mfma_f32_16x16x32_bf16(A, vf[KS][g][0], acc[0][g], 0, 0, 0); \
        acc[1][g] = __builtin_amdgcn_mfma_f32_16x16x32_bf16(A, vf[KS][g][1], acc[1][g], 0, 0, 0); \
      }
    DOKS(a0, 0) DOKS(a1, 1) DOKS(a2, 2) DOKS(a3, 3)
    #undef DOKS

    // partial (per-wave k-window) -> LDS; only lanes with valid rows (kq<2)
    if (kq < 2) {
      #pragma unroll
      for (int ct = 0; ct < 2; ++ct)
        #pragma unroll
        for (int g = 0; g < 4; ++g)
          #pragma unroll
          for (int r = 0; r < 4; ++r)
            gbuf[(w << 10) + (((kq << 2) + r) << 7) + (((ct << 4) + lm) << 2) + g] = acc[ct][g][r];
    }

    __syncthreads();

    if (cellown) {
      const int off = (b << 7) + (cc << 2);
      f32x4 hv = *(const f32x4*)(gbuf + off);
      #pragma unroll
      for (int w2 = 1; w2 < 8; ++w2)
        hv += *(const f32x4*)(gbuf + (w2 << 10) + off);

      const float pn = hv[0] + gp[0] + bias_r[0];
      const float pi = hv[1] + gp[1] + bias_r[1];
      const float pf = hv[2] + gp[2] + bias_r[2];
      const float po = hv[3] + gp[3] + bias_r[3];
      const float nn = tanhf_(pn);
      const float ii = sigf(pi);
      const float ff = sigf(pf);
      const float oo = sigf(po);
      c = c * ff + nn * ii;
      const float h = tanhf_(c) * oo;

      // tagged write-through h store: payload + tag in one atomic dword
      const uint32_t* sp = hb32 + (((t + 1) & 1) << 16) + (gr << 10) + jh + cc;
      const uint32_t hw = (((uint32_t)f2bf(h)) << 16) | ((uint32_t)(t + 1) & 0xFFFFu);
      asm volatile("global_store_dword %0, %1, off sc0 sc1"
                   :: "v"(sp), "v"(hw) : "memory");

      out[(size_t)gr * 524288 + ((size_t)t << 10) + jh + cc] = h;
      if (t == 511) {
        out[OUT_HF + (gr << 10) + jh + cc] = h;
        out[OUT_CF + (gr << 10) + jh + cc] = c;
      }
      #pragma unroll
      for (int g = 0; g < 4; ++g) gp[g] = gn[g];
    }

    // drain h stores (per-wave), join all waves, then publish the flag.
    // (also protects gbuf for the next iteration)
    asm volatile("s_waitcnt vmcnt(0)" ::: "memory");
    __syncthreads();
    if (tid == 0) {
      const uint32_t fw = (uint32_t)(t + 1);
      asm volatile("global_store_dword %0, %1, off sc0 sc1"
                   :: "v"(fmine), "v"(fw) : "memory");
    }
  }
}

extern "C" void kernel_launch(void* const* d_in, const int* in_sizes, int n_in,
                              void* d_out, int out_size, void* d_ws, size_t ws_size,
                              hipStream_t stream) {
  const float* x  = (const float*)d_in[0];
  const float* U  = (const float*)d_in[1];
  const float* V  = (const float*)d_in[2];
  const float* Bi = (const float*)d_in[3];
  const float* h0 = (const float*)d_in[4];
  const float* c0 = (const float*)d_in[5];
  float* out = (float*)d_out;
  char* ws = (char*)d_ws;

  unsigned short* Gb = (unsigned short*)(ws + WS_G);
  unsigned short* xb = (unsigned short*)(ws + WS_XB);
  unsigned short* ut = (unsigned short*)(ws + WS_UT);
  uint32_t* hb32     = (uint32_t*)(ws + WS_HB);
  uint32_t* flg      = (uint32_t*)(ws + WS_FL);

  convert_x  <<<32768, 256, 0, stream>>>(x, xb);
  transpose_u<<<dim3(16, 64), 256, 0, stream>>>(U, ut);
  gemm_xu    <<<8192, 256, 0, stream>>>(xb, ut, Gb);
  // init_h AFTER gemm_xu: hb32/flags alias xb's storage
  init_h     <<<256, 256, 0, stream>>>(h0, hb32, flg);
  lstm_rec   <<<256, 512, 0, stream>>>(Gb, V, Bi, c0, hb32, flg, out);
}